// Round 16
// baseline (265.144 us; speedup 1.0000x reference)
//
#include <hip/hip_runtime.h>
#include <cstdint>
#include <cstddef>

#define B_   8
#define S_   1024
#define D_   768
#define H_   12
#define DK_  64
#define DFF_ 3072
#define M_   (B_*S_)   // 8192 token rows

typedef __attribute__((ext_vector_type(8))) short  short8;
typedef __attribute__((ext_vector_type(8))) __bf16 bf16x8;
typedef __attribute__((ext_vector_type(4))) float  f32x4;
typedef __attribute__((ext_vector_type(4))) unsigned uint4v;
typedef __attribute__((ext_vector_type(2))) unsigned uint2v;

__device__ __forceinline__ unsigned short f2bf(float f) {
    unsigned u = __builtin_bit_cast(unsigned, f);
    u += 0x7FFFu + ((u >> 16) & 1u);           // RNE
    return (unsigned short)(u >> 16);
}

__device__ __forceinline__ unsigned pkbf(float a, float b) {
    unsigned short ua = __builtin_bit_cast(unsigned short, (__bf16)a);
    unsigned short ub = __builtin_bit_cast(unsigned short, (__bf16)b);
    return (unsigned)ua | ((unsigned)ub << 16);
}

__device__ __forceinline__ f32x4 mfma16(short8 a, short8 b, f32x4 c) {
    return __builtin_amdgcn_mfma_f32_16x16x32_bf16(
        __builtin_bit_cast(bf16x8, a), __builtin_bit_cast(bf16x8, b), c, 0, 0, 0);
}

__device__ __forceinline__ void gload16(const void* g, void* l) {
    auto gp = reinterpret_cast<const __attribute__((address_space(1))) unsigned*>(
        reinterpret_cast<uintptr_t>(g));
    auto lp = reinterpret_cast<__attribute__((address_space(3))) unsigned*>(
        reinterpret_cast<uintptr_t>(l));
    __builtin_amdgcn_global_load_lds(gp, lp, 16, 0, 0);
}

// fast GELU (tanh form), overflow-safe, ~3e-4 max abs error (<< bf16 ulp here)
__device__ __forceinline__ float gelu_fast(float v) {
    float w = v * __builtin_fmaf(v * v, 0.044715f, 1.0f);
    float e = __builtin_amdgcn_exp2f(-2.3021178f * w);   // exp2(-2u*log2e)
    return v * __builtin_amdgcn_rcpf(1.0f + e);
}

// ---- single fused weight cast+transpose: 12 slices of 768x768 ----
__global__ __launch_bounds__(256) void wtrans12_kernel(
    const float* __restrict__ Wq, const float* __restrict__ Wk,
    const float* __restrict__ Wv, const float* __restrict__ Wo,
    const float* __restrict__ W1, const float* __restrict__ W2,
    unsigned short* __restrict__ wt_qkv, unsigned short* __restrict__ wt_1,
    unsigned short* __restrict__ wt_2)
{
    __shared__ float tile[32][33];
    const int z = blockIdx.z;
    const float* src; unsigned short* dst; int sstride, dstride;
    if (z < 4) {
        src = (z == 0) ? Wq : (z == 1) ? Wk : (z == 2) ? Wv : Wo;
        dst = wt_qkv + (size_t)z * 768 * 768;
        sstride = 768; dstride = 768;
    } else if (z < 8) {
        int q = z - 4;
        src = W1 + q * 768;                       // N-slice: cols [768q,768q+768)
        dst = wt_1 + (size_t)q * 768 * 768;
        sstride = 3072; dstride = 768;
    } else {
        int q = z - 8;
        src = W2 + (size_t)q * 768 * 768;         // K-slice: rows [768q,768q+768)
        dst = wt_2 + q * 768;
        sstride = 768; dstride = 3072;
    }
    const int n0 = blockIdx.x * 32, k0 = blockIdx.y * 32;
    const int tx = threadIdx.x, ty = threadIdx.y;   // 32 x 8
#pragma unroll
    for (int j = 0; j < 4; ++j)
        tile[ty + j*8][tx] = src[(size_t)(k0 + ty + j*8) * sstride + n0 + tx];
    __syncthreads();
#pragma unroll
    for (int j = 0; j < 4; ++j)
        dst[(size_t)(n0 + ty + j*8) * dstride + k0 + tx] = f2bf(tile[tx][ty + j*8]);
}

// ---- LayerNorm fp32 -> bf16, one row (768) per block of 256 ----
__global__ __launch_bounds__(256) void ln_kernel(
    const float* __restrict__ x, const float* __restrict__ g,
    const float* __restrict__ b, unsigned short* __restrict__ out)
{
    int row = blockIdx.x, t = threadIdx.x;
    const float* xr = x + (size_t)row * D_;
    float v[3];
#pragma unroll
    for (int i = 0; i < 3; ++i) v[i] = xr[t + i*256];
    float s  = v[0] + v[1] + v[2];
    float ss = v[0]*v[0] + v[1]*v[1] + v[2]*v[2];
#pragma unroll
    for (int d = 1; d < 64; d <<= 1) { s += __shfl_xor(s, d); ss += __shfl_xor(ss, d); }
    __shared__ float red[8];
    int w = t >> 6, lane = t & 63;
    if (lane == 0) { red[w] = s; red[4 + w] = ss; }
    __syncthreads();
    s  = red[0] + red[1] + red[2] + red[3];
    ss = red[4] + red[5] + red[6] + red[7];
    float mu   = s * (1.0f / D_);
    float var  = ss * (1.0f / D_) - mu * mu;
    float rstd = rsqrtf(var + 1e-5f);
    unsigned short* orow = out + (size_t)row * D_;
#pragma unroll
    for (int i = 0; i < 3; ++i) {
        int c = t + i*256;
        orow[c] = f2bf((v[i] - mu) * rstd * g[c] + b[c]);
    }
}

// ---- pipelined GEMM BN=128 (r15-verified): BM=128, BK=64, depth-2 ----
template<int EPI>
__global__ __launch_bounds__(256, 2) void gemm_kernel(
    const unsigned short* __restrict__ A, const unsigned short* __restrict__ Wt,
    const float* __restrict__ bias, const float* __restrict__ resid,
    void* __restrict__ outp, int N, int K)
{
    __shared__ unsigned short Al[2][128*64];
    __shared__ unsigned short Bl[2][128*64];
    constexpr int ASH = 4, BSH = 4;
    const int nwg = gridDim.x;
    const int p = blockIdx.x;
    const int cpx = nwg >> 3;
    const int xcd = p & 7, id = p >> 3;
    const int nbn = N >> 7;
    const int rowsX = cpx / nbn;
    const int hn = nbn >> 1, hc = cpx >> 1;
    const int half = id / hc, rr = id % hc;
    const int bm = xcd * rowsX + rr / hn;
    const int bn = half * hn + rr % hn;

    const int t = threadIdx.x;
    const int lane = t & 63, w = t >> 6;
    const int wm = w >> 1, wn = w & 1;
    const int lr = lane & 15, lh = lane >> 4;
    const char* aBase = (const char*)(A  + (size_t)(bm*128) * K);
    const char* bBase = (const char*)(Wt + (size_t)(bn*128) * K);

    uintptr_t aAdr[ASH], bAdr[BSH];
#pragma unroll
    for (int s = 0; s < ASH; ++s) {
        int d = s*4096 + t*16;
        int row = d >> 7;
        int ch  = ((d >> 4) & 7) ^ (row & 7);
        aAdr[s] = (uintptr_t)aBase + (size_t)row*(K*2) + ch*16;
    }
#pragma unroll
    for (int s = 0; s < BSH; ++s) {
        int d = s*4096 + t*16;
        int row = d >> 7;
        int ch  = ((d >> 4) & 7) ^ (row & 7);
        bAdr[s] = (uintptr_t)bBase + (size_t)row*(K*2) + ch*16;
    }

    f32x4 acc[4][4] = {};

    auto stage = [&](int kt, int buf) {
        const int k0b = kt << 7;
#pragma unroll
        for (int s = 0; s < ASH; ++s)
            gload16((const void*)(aAdr[s] + k0b), (char*)&Al[buf][0] + s*4096 + t*16);
#pragma unroll
        for (int s = 0; s < BSH; ++s)
            gload16((const void*)(bAdr[s] + k0b), (char*)&Bl[buf][0] + s*4096 + t*16);
    };

    const int nk = K >> 6;
    stage(0, 0);
    stage(1, 1);

    for (int it = 0; it < nk; ++it) {
        const int buf = it & 1;
        if (it + 1 < nk) asm volatile("s_waitcnt vmcnt(8)" ::: "memory");
        else             asm volatile("s_waitcnt vmcnt(0)" ::: "memory");
        __builtin_amdgcn_s_barrier();

        short8 xf[2][4], wf[2][4];
#pragma unroll
        for (int kk = 0; kk < 2; ++kk) {
#pragma unroll
            for (int i = 0; i < 4; ++i)
                xf[kk][i] = *reinterpret_cast<const short8*>(
                    &Al[buf][(wm*64 + i*16 + lr)*64 + (((kk*4 + lh) ^ (lr & 7))*8)]);
#pragma unroll
            for (int j = 0; j < 4; ++j)
                wf[kk][j] = *reinterpret_cast<const short8*>(
                    &Bl[buf][(wn*64 + j*16 + lr)*64 + (((kk*4 + lh) ^ (lr & 7))*8)]);
        }
        __builtin_amdgcn_s_setprio(1);
#pragma unroll
        for (int kk = 0; kk < 2; ++kk)
#pragma unroll
            for (int i = 0; i < 4; ++i)
#pragma unroll
                for (int j = 0; j < 4; ++j)
                    acc[i][j] = mfma16(wf[kk][j], xf[kk][i], acc[i][j]);   // D = W·X^T
        __builtin_amdgcn_s_setprio(0);
        __builtin_amdgcn_s_barrier();
        if (it + 2 < nk) stage(it + 2, buf);
    }

#pragma unroll
    for (int i = 0; i < 4; ++i) {
        const int m = bm*128 + wm*64 + i*16 + lr;
#pragma unroll
        for (int j = 0; j < 4; ++j) {
            const int n0 = bn*128 + wn*64 + j*16 + lh*4;
            f32x4 v = acc[i][j];
            if (EPI == 1) {
                f32x4 bb = *reinterpret_cast<const f32x4*>(&bias[n0]);
                v += bb;
#pragma unroll
                for (int r = 0; r < 4; ++r) v[r] = gelu_fast(v[r]);
            }
            if (EPI == 2) {
                if (bias) v += *reinterpret_cast<const f32x4*>(&bias[n0]);
                v += *reinterpret_cast<const f32x4*>(&resid[(size_t)m*N + n0]);
                *reinterpret_cast<f32x4*>(&((float*)outp)[(size_t)m*N + n0]) = v;
            } else {
                uint2v pv = { pkbf(v[0], v[1]), pkbf(v[2], v[3]) };
                *reinterpret_cast<uint2v*>(&((unsigned short*)outp)[(size_t)m*N + n0]) = pv;
            }
        }
    }
}

// ---- BN=64 GEMM: ONE-BARRIER TRI-BUFFER (new this round) ----
// stage(it+2) after the single barrier targets buf (it-1)%3 whose reads
// completed before every wave reached this barrier (ds_read results consumed
// by pre-barrier MFMAs). Steady vmcnt(6) = next tile's loads in flight;
// prefetch distance ~2 iters. LDS 72KB -> 2 blocks/CU.
template<int EPI>
__global__ __launch_bounds__(256, 2) void gemm3_kernel(
    const unsigned short* __restrict__ A, const unsigned short* __restrict__ Wt,
    const float* __restrict__ bias, const float* __restrict__ resid,
    void* __restrict__ outp, int N, int K)
{
    __shared__ unsigned short Al[3][128*64];   // 48KB
    __shared__ unsigned short Bl[3][64*64];    // 24KB
    constexpr int ASH = 4, BSH = 2;
    const int nwg = gridDim.x;
    const int p = blockIdx.x;
    const int cpx = nwg >> 3;
    const int xcd = p & 7, id = p >> 3;
    const int nbn = N >> 6;
    const int rowsX = cpx / nbn;
    const int hn = nbn >> 1, hc = cpx >> 1;
    const int half = id / hc, rr = id % hc;
    const int bm = xcd * rowsX + rr / hn;
    const int bn = half * hn + rr % hn;

    const int t = threadIdx.x;
    const int lane = t & 63, w = t >> 6;
    const int wm = w >> 1, wn = w & 1;
    const int lr = lane & 15, lh = lane >> 4;
    const char* aBase = (const char*)(A  + (size_t)(bm*128) * K);
    const char* bBase = (const char*)(Wt + (size_t)(bn*64)  * K);

    uintptr_t aAdr[ASH], bAdr[BSH];
#pragma unroll
    for (int s = 0; s < ASH; ++s) {
        int d = s*4096 + t*16;
        int row = d >> 7;
        int ch  = ((d >> 4) & 7) ^ (row & 7);
        aAdr[s] = (uintptr_t)aBase + (size_t)row*(K*2) + ch*16;
    }
#pragma unroll
    for (int s = 0; s < BSH; ++s) {
        int d = s*4096 + t*16;
        int row = d >> 7;
        int ch  = ((d >> 4) & 7) ^ (row & 7);
        bAdr[s] = (uintptr_t)bBase + (size_t)row*(K*2) + ch*16;
    }

    f32x4 acc[4][2] = {};

    auto stage = [&](int kt, int buf) {
        const int k0b = kt << 7;
#pragma unroll
        for (int s = 0; s < ASH; ++s)
            gload16((const void*)(aAdr[s] + k0b), (char*)&Al[buf][0] + s*4096 + t*16);
#pragma unroll
        for (int s = 0; s < BSH; ++s)
            gload16((const void*)(bAdr[s] + k0b), (char*)&Bl[buf][0] + s*4096 + t*16);
    };

    const int nk = K >> 6;
    stage(0, 0);
    stage(1, 1);

    int buf = 0;
    for (int it = 0; it < nk; ++it) {
        if (it + 1 < nk) asm volatile("s_waitcnt vmcnt(6)" ::: "memory");
        else             asm volatile("s_waitcnt vmcnt(0)" ::: "memory");
        __builtin_amdgcn_s_barrier();
        if (it + 2 < nk) stage(it + 2, buf == 0 ? 2 : buf - 1);

        short8 xf[2][4], wf[2][2];
#pragma unroll
        for (int kk = 0; kk < 2; ++kk) {
#pragma unroll
            for (int i = 0; i < 4; ++i)
                xf[kk][i] = *reinterpret_cast<const short8*>(
                    &Al[buf][(wm*64 + i*16 + lr)*64 + (((kk*4 + lh) ^ (lr & 7))*8)]);
#pragma unroll
            for (int j = 0; j < 2; ++j)
                wf[kk][j] = *reinterpret_cast<const short8*>(
                    &Bl[buf][(wn*32 + j*16 + lr)*64 + (((kk*4 + lh) ^ (lr & 7))*8)]);
        }
        __builtin_amdgcn_s_setprio(1);
#pragma unroll
        for (int kk = 0; kk < 2; ++kk)
#pragma unroll
            for (int i = 0; i < 4; ++i)
#pragma unroll
                for (int j = 0; j < 2; ++j)
                    acc[i][j] = mfma16(wf[kk][j], xf[kk][i], acc[i][j]);   // D = W·X^T
        __builtin_amdgcn_s_setprio(0);
        buf = (buf == 2) ? 0 : buf + 1;
    }

#pragma unroll
    for (int i = 0; i < 4; ++i) {
        const int m = bm*128 + wm*64 + i*16 + lr;
#pragma unroll
        for (int j = 0; j < 2; ++j) {
            const int n0 = bn*64 + wn*32 + j*16 + lh*4;
            f32x4 v = acc[i][j];
            if (EPI == 1) {
                f32x4 bb = *reinterpret_cast<const f32x4*>(&bias[n0]);
                v += bb;
#pragma unroll
                for (int r = 0; r < 4; ++r) v[r] = gelu_fast(v[r]);
            }
            if (EPI == 2) {
                if (bias) v += *reinterpret_cast<const f32x4*>(&bias[n0]);
                v += *reinterpret_cast<const f32x4*>(&resid[(size_t)m*N + n0]);
                *reinterpret_cast<f32x4*>(&((float*)outp)[(size_t)m*N + n0]) = v;
            } else {
                uint2v pv = { pkbf(v[0], v[1]), pkbf(v[2], v[3]) };
                *reinterpret_cast<uint2v*>(&((unsigned short*)outp)[(size_t)m*N + n0]) = pv;
            }
        }
    }
}

// ---- V transpose + PV k-permutation (r15-verified) ----
__global__ __launch_bounds__(256) void vtrans_kernel(
    const unsigned short* __restrict__ qkv, unsigned short* __restrict__ vt)
{
    __shared__ unsigned short tl[64][65];
    int bid = blockIdx.x;
    int sblk = bid & 15, bh = bid >> 4;
    int b = bh / H_, h = bh % H_;
    int t = threadIdx.x, tx = t & 63, ty = t >> 6;
    int s0 = sblk * 64;
#pragma unroll
    for (int j = 0; j < 16; ++j) {
        int s = j*4 + ty;
        tl[s][tx] = qkv[(size_t)(b*S_ + s0 + s)*2304 + 1536 + h*64 + tx];
    }
    __syncthreads();
    const int lh2 = (tx >> 3) & 3, e2 = tx & 7;
    const int psrc = (tx & 32) |
        ((e2 < 4) ? (lh2*4 + e2) : (16 + lh2*4 + (e2 - 4)));
#pragma unroll
    for (int j = 0; j < 16; ++j) {
        int dk = j*4 + ty;
        vt[((size_t)bh*64 + dk)*S_ + s0 + tx] = tl[psrc][dk];
    }
}

// ---- flash attention v6 (r15-verified) ----
__global__ __launch_bounds__(256, 3) void attn_kernel(
    const unsigned short* __restrict__ qkv, const unsigned short* __restrict__ vt,
    unsigned short* __restrict__ out)
{
    __shared__ unsigned short Kl[2][64*64];
    __shared__ unsigned short Vl[2][64*64];

    const int p = blockIdx.x;
    const int l = (p & 7) * 96 + (p >> 3);
    const int qb = l & 7, bh = l >> 3;
    const int b = bh / H_, h = bh % H_;
    const int t = threadIdx.x, lane = t & 63, w = t >> 6;
    const int lr = lane & 15, lh = lane >> 4;
    const int sz = (lr & 7) << 3;

    const float SC = 0.125f * 1.44269504089f;
    const float SHIFT = 12.0f;

    const int qrow0 = qb*128 + w*32;
    short8 bq[2][2];
#pragma unroll
    for (int qi = 0; qi < 2; ++qi) {
        const unsigned short* qp = qkv + (size_t)(b*S_ + qrow0 + qi*16 + lr)*2304 + h*64;
#pragma unroll
        for (int c = 0; c < 2; ++c)
            bq[qi][c] = *reinterpret_cast<const short8*>(&qp[c*32 + lh*8]);
    }

    float l_run[2] = {0.f, 0.f};
    f32x4 o[2][4] = {};

    uintptr_t kAdr[2], vAdr[2];
#pragma unroll
    for (int shot = 0; shot < 2; ++shot) {
        int d = shot*4096 + t*16;
        int row = d >> 7;
        int sc = (d & 127) ^ ((row & 7) << 4);
        kAdr[shot] = (uintptr_t)qkv + ((size_t)(b*S_ + row)*2304 + 768 + h*64)*2 + sc;
        vAdr[shot] = (uintptr_t)vt  + ((size_t)(bh*64 + row)*1024)*2 + sc;
    }

    auto stage = [&](int kb, int buf) {
        const size_t kOff = (size_t)kb * 64 * 2304 * 2;
        const size_t vOff = (size_t)kb * 128;
#pragma unroll
        for (int shot = 0; shot < 2; ++shot) {
            int d = shot*4096 + t*16;
            gload16((const void*)(kAdr[shot] + kOff), (char*)&Kl[buf][0] + d);
            gload16((const void*)(vAdr[shot] + vOff), (char*)&Vl[buf][0] + d);
        }
    };

    stage(0, 0);
    asm volatile("s_waitcnt vmcnt(0)" ::: "memory");
    __builtin_amdgcn_s_barrier();

    for (int kb = 0; kb < 16; ++kb) {
        const int buf = kb & 1;
        if (kb < 15) stage(kb + 1, buf ^ 1);

        short8 ak[4][2];
#pragma unroll
        for (int j = 0; j < 4; ++j)
#pragma unroll
            for (int c = 0; c < 2; ++c)
                ak[j][c] = *reinterpret_cast<const short8*>(
                    &Kl[buf][(j*16 + lr)*64 + ((c*32 + lh*8) ^ sz)]);

        short8 av[4][2];
#pragma unroll
        for (int j = 0; j < 4; ++j) {
            const unsigned short* vrow = &Vl[buf][(j*16 + lr)*64];
#pragma unroll
            for (int ks = 0; ks < 2; ++ks)
                av[j][ks] = *reinterpret_cast<const short8*>(
                    &vrow[(ks*32 + lh*8) ^ sz]);
        }

#pragma unroll
        for (int qi = 0; qi < 2; ++qi) {
            f32x4 s[4];
            __builtin_amdgcn_s_setprio(1);
#pragma unroll
            for (int j = 0; j < 4; ++j) {
                f32x4 z = {0.f, 0.f, 0.f, 0.f};
                z = mfma16(ak[j][0], bq[qi][0], z);
                z = mfma16(ak[j][1], bq[qi][1], z);
                s[j] = z;
            }
            __builtin_amdgcn_s_setprio(0);

            float rs = 0.f;
#pragma unroll
            for (int j = 0; j < 4; ++j)
#pragma unroll
                for (int r = 0; r < 4; ++r) {
                    float pv = __builtin_amdgcn_exp2f(
                        __builtin_fmaf(s[j][r], SC, -SHIFT));
                    s[j][r] = pv;
                    rs += pv;
                }
            l_run[qi] += rs;

            uint4v u0 = { pkbf(s[0][0], s[0][1]), pkbf(s[0][2], s[0][3]),
                          pkbf(s[1][0], s[1][1]), pkbf(s[1][2], s[1][3]) };
            uint4v u1 = { pkbf(s[2][0], s[2][1]), pkbf(s[2][2], s[2][3]),
                          pkbf(s[3][0], s[3][1]), pkbf(s[3][2], s[3][3]) };
            short8 pb0 = __builtin_bit_cast(short8, u0);
            short8 pb1 = __builtin_bit_cast(short8, u1);

            __builtin_amdgcn_s_setprio(1);
#pragma unroll
            for (int j = 0; j < 4; ++j) {
                o[qi][j] = mfma16(av[j][0], pb0, o[qi][j]);
                o[qi][j] = mfma16(av[j][1], pb1, o[qi][j]);
            }
            __builtin_amdgcn_s_setprio(0);
        }

        asm volatile("s_waitcnt vmcnt(0)" ::: "memory");
        __builtin_amdgcn_s_barrier();
    }

#pragma unroll
    for (int qi = 0; qi < 2; ++qi) {
        float ls = l_run[qi];
        ls += __shfl_xor(ls, 16);
        ls += __shfl_xor(ls, 32);
        float inv = 1.0f / ls;
        int q = qrow0 + qi*16 + lr;
        unsigned short* orow = out + (size_t)(b*S_ + q)*D_ + h*64;
#pragma unroll
        for (int j = 0; j < 4; ++j) {
            uint2v vv = { pkbf(o[qi][j][0]*inv, o[qi][j][1]*inv),
                          pkbf(o[qi][j][2]*inv, o[qi][j][3]*inv) };
            *reinterpret_cast<uint2v*>(&orow[j*16 + lh*4]) = vv;
        }
    }
}

extern "C" void kernel_launch(void* const* d_in, const int* in_sizes, int n_in,
                              void* d_out, int out_size, void* d_ws, size_t ws_size,
                              hipStream_t stream)
{
    (void)in_sizes; (void)n_in; (void)out_size; (void)ws_size;
    const float* x   = (const float*)d_in[0];
    const float* Wq  = (const float*)d_in[1];
    const float* Wk  = (const float*)d_in[2];
    const float* Wv  = (const float*)d_in[3];
    const float* Wo  = (const float*)d_in[4];
    const float* g1  = (const float*)d_in[5];
    const float* b1  = (const float*)d_in[6];
    const float* g2  = (const float*)d_in[7];
    const float* b2  = (const float*)d_in[8];
    const float* W1  = (const float*)d_in[9];
    const float* bW1 = (const float*)d_in[10];
    const float* W2  = (const float*)d_in[11];
    const float* bW2 = (const float*)d_in[12];
    float* out = (float*)d_out;

    char* ws = (char*)d_ws;
    unsigned short* wt_qkv = (unsigned short*)(ws);            // [2304][768] + wt_o after
    unsigned short* wt_o   = (unsigned short*)(ws + 3538944);  // [768][768]
    unsigned short* wt_1   = (unsigned short*)(ws + 4718592);  // [3072][768]
    unsigned short* wt_2   = (unsigned short*)(ws + 9437184);  // [768][3072]
    unsigned short* slotA  = (unsigned short*)(ws + 14155776); // [8192][768] bf16
    unsigned short* qkv    = (unsigned short*)(ws + 26738688); // [8192][2304] bf16
    unsigned short* vt     = (unsigned short*)(ws + 64487424); // [96][64][1024] bf16
    unsigned short* ffm    = qkv;                              // [8192][3072] bf16 (reuse)

    dim3 tb(32, 8);
    wtrans12_kernel<<<dim3(24,24,12), tb, 0, stream>>>(
        Wq, Wk, Wv, Wo, W1, W2, wt_qkv, wt_1, wt_2);

    ln_kernel<<<M_, 256, 0, stream>>>(x, g1, b1, slotA);
    gemm_kernel<0><<<1152, 256, 0, stream>>>(slotA, wt_qkv, nullptr, nullptr, qkv, 2304, 768);
    vtrans_kernel<<<1536, 256, 0, stream>>>(qkv, vt);
    attn_kernel<<<768, 256, 0, stream>>>(qkv, vt, slotA);
    gemm3_kernel<2><<<768, 256, 0, stream>>>(slotA, wt_o, nullptr, x, (void*)out, 768, 768);
    ln_kernel<<<M_, 256, 0, stream>>>(out, g2, b2, slotA);
    gemm_kernel<1><<<1536, 256, 0, stream>>>(slotA, wt_1, bW1, nullptr, ffm, 3072, 768);
    gemm3_kernel<2><<<768, 256, 0, stream>>>(ffm, wt_2, bW2, out, (void*)out, 768, 3072);
}

// Round 17
// 251.429 us; speedup vs baseline: 1.0545x; 1.0545x over previous
//
#include <hip/hip_runtime.h>
#include <cstdint>
#include <cstddef>

#define B_   8
#define S_   1024
#define D_   768
#define H_   12
#define DK_  64
#define DFF_ 3072
#define M_   (B_*S_)   // 8192 token rows

typedef __attribute__((ext_vector_type(8))) short  short8;
typedef __attribute__((ext_vector_type(8))) __bf16 bf16x8;
typedef __attribute__((ext_vector_type(4))) float  f32x4;
typedef __attribute__((ext_vector_type(4))) unsigned uint4v;
typedef __attribute__((ext_vector_type(2))) unsigned uint2v;

__device__ __forceinline__ unsigned short f2bf(float f) {
    unsigned u = __builtin_bit_cast(unsigned, f);
    u += 0x7FFFu + ((u >> 16) & 1u);           // RNE
    return (unsigned short)(u >> 16);
}

__device__ __forceinline__ unsigned pkbf(float a, float b) {
    unsigned short ua = __builtin_bit_cast(unsigned short, (__bf16)a);
    unsigned short ub = __builtin_bit_cast(unsigned short, (__bf16)b);
    return (unsigned)ua | ((unsigned)ub << 16);
}

__device__ __forceinline__ f32x4 mfma16(short8 a, short8 b, f32x4 c) {
    return __builtin_amdgcn_mfma_f32_16x16x32_bf16(
        __builtin_bit_cast(bf16x8, a), __builtin_bit_cast(bf16x8, b), c, 0, 0, 0);
}

__device__ __forceinline__ void gload16(const void* g, void* l) {
    auto gp = reinterpret_cast<const __attribute__((address_space(1))) unsigned*>(
        reinterpret_cast<uintptr_t>(g));
    auto lp = reinterpret_cast<__attribute__((address_space(3))) unsigned*>(
        reinterpret_cast<uintptr_t>(l));
    __builtin_amdgcn_global_load_lds(gp, lp, 16, 0, 0);
}

// fast GELU (tanh form), overflow-safe, ~3e-4 max abs error (<< bf16 ulp here)
__device__ __forceinline__ float gelu_fast(float v) {
    float w = v * __builtin_fmaf(v * v, 0.044715f, 1.0f);
    float e = __builtin_amdgcn_exp2f(-2.3021178f * w);   // exp2(-2u*log2e)
    return v * __builtin_amdgcn_rcpf(1.0f + e);
}

// ---- single fused weight cast+transpose: 12 slices of 768x768 ----
__global__ __launch_bounds__(256) void wtrans12_kernel(
    const float* __restrict__ Wq, const float* __restrict__ Wk,
    const float* __restrict__ Wv, const float* __restrict__ Wo,
    const float* __restrict__ W1, const float* __restrict__ W2,
    unsigned short* __restrict__ wt_qkv, unsigned short* __restrict__ wt_1,
    unsigned short* __restrict__ wt_2)
{
    __shared__ float tile[32][33];
    const int z = blockIdx.z;
    const float* src; unsigned short* dst; int sstride, dstride;
    if (z < 4) {
        src = (z == 0) ? Wq : (z == 1) ? Wk : (z == 2) ? Wv : Wo;
        dst = wt_qkv + (size_t)z * 768 * 768;
        sstride = 768; dstride = 768;
    } else if (z < 8) {
        int q = z - 4;
        src = W1 + q * 768;                       // N-slice: cols [768q,768q+768)
        dst = wt_1 + (size_t)q * 768 * 768;
        sstride = 3072; dstride = 768;
    } else {
        int q = z - 8;
        src = W2 + (size_t)q * 768 * 768;         // K-slice: rows [768q,768q+768)
        dst = wt_2 + q * 768;
        sstride = 768; dstride = 3072;
    }
    const int n0 = blockIdx.x * 32, k0 = blockIdx.y * 32;
    const int tx = threadIdx.x, ty = threadIdx.y;   // 32 x 8
#pragma unroll
    for (int j = 0; j < 4; ++j)
        tile[ty + j*8][tx] = src[(size_t)(k0 + ty + j*8) * sstride + n0 + tx];
    __syncthreads();
#pragma unroll
    for (int j = 0; j < 4; ++j)
        dst[(size_t)(n0 + ty + j*8) * dstride + k0 + tx] = f2bf(tile[tx][ty + j*8]);
}

// ---- LayerNorm fp32 -> bf16, one row (768) per block of 256 ----
__global__ __launch_bounds__(256) void ln_kernel(
    const float* __restrict__ x, const float* __restrict__ g,
    const float* __restrict__ b, unsigned short* __restrict__ out)
{
    int row = blockIdx.x, t = threadIdx.x;
    const float* xr = x + (size_t)row * D_;
    float v[3];
#pragma unroll
    for (int i = 0; i < 3; ++i) v[i] = xr[t + i*256];
    float s  = v[0] + v[1] + v[2];
    float ss = v[0]*v[0] + v[1]*v[1] + v[2]*v[2];
#pragma unroll
    for (int d = 1; d < 64; d <<= 1) { s += __shfl_xor(s, d); ss += __shfl_xor(ss, d); }
    __shared__ float red[8];
    int w = t >> 6, lane = t & 63;
    if (lane == 0) { red[w] = s; red[4 + w] = ss; }
    __syncthreads();
    s  = red[0] + red[1] + red[2] + red[3];
    ss = red[4] + red[5] + red[6] + red[7];
    float mu   = s * (1.0f / D_);
    float var  = ss * (1.0f / D_) - mu * mu;
    float rstd = rsqrtf(var + 1e-5f);
    unsigned short* orow = out + (size_t)row * D_;
#pragma unroll
    for (int i = 0; i < 3; ++i) {
        int c = t + i*256;
        orow[c] = f2bf((v[i] - mu) * rstd * g[c] + b[c]);
    }
}

// ---- pipelined GEMM (r15-verified): BM=128, BK=64, depth-2 counted vmcnt ----
// Two-half bn raster per XCD (L2 working-set fit). Swapped-operand MFMA.
// EPI 0: store bf16 | EPI 1: +bias, fast-gelu, store bf16 | EPI 2: (+bias)+resid, fp32
template<int BN, int EPI>
__global__ __launch_bounds__(256, 2) void gemm_kernel(
    const unsigned short* __restrict__ A, const unsigned short* __restrict__ Wt,
    const float* __restrict__ bias, const float* __restrict__ resid,
    void* __restrict__ outp, int N, int K)
{
    __shared__ unsigned short Al[2][128*64];
    __shared__ unsigned short Bl[2][BN*64];
    constexpr int NJ = BN / 64;               // 2 or 1
    constexpr int ASH = 4, BSH = 2*NJ;
    const int nwg = gridDim.x;
    const int p = blockIdx.x;
    const int cpx = nwg >> 3;
    const int xcd = p & 7, id = p >> 3;
    const int nbn = N / BN;
    const int rowsX = cpx / nbn;
    const int hn = nbn >> 1, hc = cpx >> 1;
    const int half = id / hc, rr = id % hc;
    const int bm = xcd * rowsX + rr / hn;
    const int bn = half * hn + rr % hn;

    const int t = threadIdx.x;
    const int lane = t & 63, w = t >> 6;
    const int wm = w >> 1, wn = w & 1;
    const int lr = lane & 15, lh = lane >> 4;
    const char* aBase = (const char*)(A  + (size_t)(bm*128) * K);
    const char* bBase = (const char*)(Wt + (size_t)(bn*BN)  * K);

    uintptr_t aAdr[ASH], bAdr[BSH];
#pragma unroll
    for (int s = 0; s < ASH; ++s) {
        int d = s*4096 + t*16;
        int row = d >> 7;
        int ch  = ((d >> 4) & 7) ^ (row & 7);
        aAdr[s] = (uintptr_t)aBase + (size_t)row*(K*2) + ch*16;
    }
#pragma unroll
    for (int s = 0; s < BSH; ++s) {
        int d = s*4096 + t*16;
        int row = d >> 7;
        int ch  = ((d >> 4) & 7) ^ (row & 7);
        bAdr[s] = (uintptr_t)bBase + (size_t)row*(K*2) + ch*16;
    }

    f32x4 acc[4][2*NJ] = {};

    auto stage = [&](int kt, int buf) {
        const int k0b = kt << 7;              // byte offset along K
#pragma unroll
        for (int s = 0; s < ASH; ++s)
            gload16((const void*)(aAdr[s] + k0b), (char*)&Al[buf][0] + s*4096 + t*16);
#pragma unroll
        for (int s = 0; s < BSH; ++s)
            gload16((const void*)(bAdr[s] + k0b), (char*)&Bl[buf][0] + s*4096 + t*16);
    };

    const int nk = K >> 6;
    stage(0, 0);
    stage(1, 1);

    for (int it = 0; it < nk; ++it) {
        const int buf = it & 1;
        if (it + 1 < nk) {
            if constexpr (BN == 128) asm volatile("s_waitcnt vmcnt(8)" ::: "memory");
            else                     asm volatile("s_waitcnt vmcnt(6)" ::: "memory");
        } else {
            asm volatile("s_waitcnt vmcnt(0)" ::: "memory");
        }
        __builtin_amdgcn_s_barrier();

        short8 xf[2][4], wf[2][2*NJ];
#pragma unroll
        for (int kk = 0; kk < 2; ++kk) {
#pragma unroll
            for (int i = 0; i < 4; ++i)
                xf[kk][i] = *reinterpret_cast<const short8*>(
                    &Al[buf][(wm*64 + i*16 + lr)*64 + (((kk*4 + lh) ^ (lr & 7))*8)]);
#pragma unroll
            for (int j = 0; j < 2*NJ; ++j)
                wf[kk][j] = *reinterpret_cast<const short8*>(
                    &Bl[buf][(wn*(32*NJ) + j*16 + lr)*64 + (((kk*4 + lh) ^ (lr & 7))*8)]);
        }
        __builtin_amdgcn_s_setprio(1);
#pragma unroll
        for (int kk = 0; kk < 2; ++kk)
#pragma unroll
            for (int i = 0; i < 4; ++i)
#pragma unroll
                for (int j = 0; j < 2*NJ; ++j)
                    acc[i][j] = mfma16(wf[kk][j], xf[kk][i], acc[i][j]);   // D = W·X^T
        __builtin_amdgcn_s_setprio(0);
        __builtin_amdgcn_s_barrier();
        if (it + 2 < nk) stage(it + 2, buf);
    }

    // epilogue: lane = M-row (i*16+lr), regs = 4 consecutive N (j*16+lh*4+r)
#pragma unroll
    for (int i = 0; i < 4; ++i) {
        const int m = bm*128 + wm*64 + i*16 + lr;
#pragma unroll
        for (int j = 0; j < 2*NJ; ++j) {
            const int n0 = bn*BN + wn*(32*NJ) + j*16 + lh*4;
            f32x4 v = acc[i][j];
            if (EPI == 1) {
                f32x4 bb = *reinterpret_cast<const f32x4*>(&bias[n0]);
                v += bb;
#pragma unroll
                for (int r = 0; r < 4; ++r) v[r] = gelu_fast(v[r]);
            }
            if (EPI == 2) {
                if (bias) v += *reinterpret_cast<const f32x4*>(&bias[n0]);
                v += *reinterpret_cast<const f32x4*>(&resid[(size_t)m*N + n0]);
                *reinterpret_cast<f32x4*>(&((float*)outp)[(size_t)m*N + n0]) = v;
            } else {
                uint2v pv = { pkbf(v[0], v[1]), pkbf(v[2], v[3]) };
                *reinterpret_cast<uint2v*>(&((unsigned short*)outp)[(size_t)m*N + n0]) = pv;
            }
        }
    }
}

// ---- V transpose + PV k-permutation (r15-verified) ----
__global__ __launch_bounds__(256) void vtrans_kernel(
    const unsigned short* __restrict__ qkv, unsigned short* __restrict__ vt)
{
    __shared__ unsigned short tl[64][65];
    int bid = blockIdx.x;
    int sblk = bid & 15, bh = bid >> 4;
    int b = bh / H_, h = bh % H_;
    int t = threadIdx.x, tx = t & 63, ty = t >> 6;
    int s0 = sblk * 64;
#pragma unroll
    for (int j = 0; j < 16; ++j) {
        int s = j*4 + ty;
        tl[s][tx] = qkv[(size_t)(b*S_ + s0 + s)*2304 + 1536 + h*64 + tx];
    }
    __syncthreads();
    const int lh2 = (tx >> 3) & 3, e2 = tx & 7;
    const int psrc = (tx & 32) |
        ((e2 < 4) ? (lh2*4 + e2) : (16 + lh2*4 + (e2 - 4)));
#pragma unroll
    for (int j = 0; j < 16; ++j) {
        int dk = j*4 + ty;
        vt[((size_t)bh*64 + dk)*S_ + s0 + tx] = tl[psrc][dk];
    }
}

// ---- flash attention v6 (r15-verified) ----
__global__ __launch_bounds__(256, 3) void attn_kernel(
    const unsigned short* __restrict__ qkv, const unsigned short* __restrict__ vt,
    unsigned short* __restrict__ out)
{
    __shared__ unsigned short Kl[2][64*64];
    __shared__ unsigned short Vl[2][64*64];

    const int p = blockIdx.x;
    const int l = (p & 7) * 96 + (p >> 3);
    const int qb = l & 7, bh = l >> 3;
    const int b = bh / H_, h = bh % H_;
    const int t = threadIdx.x, lane = t & 63, w = t >> 6;
    const int lr = lane & 15, lh = lane >> 4;
    const int sz = (lr & 7) << 3;

    const float SC = 0.125f * 1.44269504089f;
    const float SHIFT = 12.0f;

    const int qrow0 = qb*128 + w*32;
    short8 bq[2][2];
#pragma unroll
    for (int qi = 0; qi < 2; ++qi) {
        const unsigned short* qp = qkv + (size_t)(b*S_ + qrow0 + qi*16 + lr)*2304 + h*64;
#pragma unroll
        for (int c = 0; c < 2; ++c)
            bq[qi][c] = *reinterpret_cast<const short8*>(&qp[c*32 + lh*8]);
    }

    float l_run[2] = {0.f, 0.f};
    f32x4 o[2][4] = {};

    uintptr_t kAdr[2], vAdr[2];
#pragma unroll
    for (int shot = 0; shot < 2; ++shot) {
        int d = shot*4096 + t*16;
        int row = d >> 7;
        int sc = (d & 127) ^ ((row & 7) << 4);
        kAdr[shot] = (uintptr_t)qkv + ((size_t)(b*S_ + row)*2304 + 768 + h*64)*2 + sc;
        vAdr[shot] = (uintptr_t)vt  + ((size_t)(bh*64 + row)*1024)*2 + sc;
    }

    auto stage = [&](int kb, int buf) {
        const size_t kOff = (size_t)kb * 64 * 2304 * 2;
        const size_t vOff = (size_t)kb * 128;
#pragma unroll
        for (int shot = 0; shot < 2; ++shot) {
            int d = shot*4096 + t*16;
            gload16((const void*)(kAdr[shot] + kOff), (char*)&Kl[buf][0] + d);
            gload16((const void*)(vAdr[shot] + vOff), (char*)&Vl[buf][0] + d);
        }
    };

    stage(0, 0);
    asm volatile("s_waitcnt vmcnt(0)" ::: "memory");
    __builtin_amdgcn_s_barrier();

    for (int kb = 0; kb < 16; ++kb) {
        const int buf = kb & 1;
        if (kb < 15) stage(kb + 1, buf ^ 1);

        short8 ak[4][2];
#pragma unroll
        for (int j = 0; j < 4; ++j)
#pragma unroll
            for (int c = 0; c < 2; ++c)
                ak[j][c] = *reinterpret_cast<const short8*>(
                    &Kl[buf][(j*16 + lr)*64 + ((c*32 + lh*8) ^ sz)]);

        short8 av[4][2];
#pragma unroll
        for (int j = 0; j < 4; ++j) {
            const unsigned short* vrow = &Vl[buf][(j*16 + lr)*64];
#pragma unroll
            for (int ks = 0; ks < 2; ++ks)
                av[j][ks] = *reinterpret_cast<const short8*>(
                    &vrow[(ks*32 + lh*8) ^ sz]);
        }

#pragma unroll
        for (int qi = 0; qi < 2; ++qi) {
            f32x4 s[4];
            __builtin_amdgcn_s_setprio(1);
#pragma unroll
            for (int j = 0; j < 4; ++j) {
                f32x4 z = {0.f, 0.f, 0.f, 0.f};
                z = mfma16(ak[j][0], bq[qi][0], z);
                z = mfma16(ak[j][1], bq[qi][1], z);
                s[j] = z;
            }
            __builtin_amdgcn_s_setprio(0);

            float rs = 0.f;
#pragma unroll
            for (int j = 0; j < 4; ++j)
#pragma unroll
                for (int r = 0; r < 4; ++r) {
                    float pv = __builtin_amdgcn_exp2f(
                        __builtin_fmaf(s[j][r], SC, -SHIFT));
                    s[j][r] = pv;
                    rs += pv;
                }
            l_run[qi] += rs;

            uint4v u0 = { pkbf(s[0][0], s[0][1]), pkbf(s[0][2], s[0][3]),
                          pkbf(s[1][0], s[1][1]), pkbf(s[1][2], s[1][3]) };
            uint4v u1 = { pkbf(s[2][0], s[2][1]), pkbf(s[2][2], s[2][3]),
                          pkbf(s[3][0], s[3][1]), pkbf(s[3][2], s[3][3]) };
            short8 pb0 = __builtin_bit_cast(short8, u0);
            short8 pb1 = __builtin_bit_cast(short8, u1);

            __builtin_amdgcn_s_setprio(1);
#pragma unroll
            for (int j = 0; j < 4; ++j) {
                o[qi][j] = mfma16(av[j][0], pb0, o[qi][j]);
                o[qi][j] = mfma16(av[j][1], pb1, o[qi][j]);
            }
            __builtin_amdgcn_s_setprio(0);
        }

        asm volatile("s_waitcnt vmcnt(0)" ::: "memory");
        __builtin_amdgcn_s_barrier();
    }

#pragma unroll
    for (int qi = 0; qi < 2; ++qi) {
        float ls = l_run[qi];
        ls += __shfl_xor(ls, 16);
        ls += __shfl_xor(ls, 32);
        float inv = 1.0f / ls;
        int q = qrow0 + qi*16 + lr;
        unsigned short* orow = out + (size_t)(b*S_ + q)*D_ + h*64;
#pragma unroll
        for (int j = 0; j < 4; ++j) {
            uint2v vv = { pkbf(o[qi][j][0]*inv, o[qi][j][1]*inv),
                          pkbf(o[qi][j][2]*inv, o[qi][j][3]*inv) };
            *reinterpret_cast<uint2v*>(&orow[j*16 + lh*4]) = vv;
        }
    }
}

extern "C" void kernel_launch(void* const* d_in, const int* in_sizes, int n_in,
                              void* d_out, int out_size, void* d_ws, size_t ws_size,
                              hipStream_t stream)
{
    (void)in_sizes; (void)n_in; (void)out_size; (void)ws_size;
    const float* x   = (const float*)d_in[0];
    const float* Wq  = (const float*)d_in[1];
    const float* Wk  = (const float*)d_in[2];
    const float* Wv  = (const float*)d_in[3];
    const float* Wo  = (const float*)d_in[4];
    const float* g1  = (const float*)d_in[5];
    const float* b1  = (const float*)d_in[6];
    const float* g2  = (const float*)d_in[7];
    const float* b2  = (const float*)d_in[8];
    const float* W1  = (const float*)d_in[9];
    const float* bW1 = (const float*)d_in[10];
    const float* W2  = (const float*)d_in[11];
    const float* bW2 = (const float*)d_in[12];
    float* out = (float*)d_out;

    char* ws = (char*)d_ws;
    unsigned short* wt_qkv = (unsigned short*)(ws);            // [2304][768] + wt_o after
    unsigned short* wt_o   = (unsigned short*)(ws + 3538944);  // [768][768]
    unsigned short* wt_1   = (unsigned short*)(ws + 4718592);  // [3072][768]
    unsigned short* wt_2   = (unsigned short*)(ws + 9437184);  // [768][3072]
    unsigned short* slotA  = (unsigned short*)(ws + 14155776); // [8192][768] bf16
    unsigned short* qkv    = (unsigned short*)(ws + 26738688); // [8192][2304] bf16
    unsigned short* vt     = (unsigned short*)(ws + 64487424); // [96][64][1024] bf16
    unsigned short* ffm    = qkv;                              // [8192][3072] bf16 (reuse)

    dim3 tb(32, 8);
    wtrans12_kernel<<<dim3(24,24,12), tb, 0, stream>>>(
        Wq, Wk, Wv, Wo, W1, W2, wt_qkv, wt_1, wt_2);

    ln_kernel<<<M_, 256, 0, stream>>>(x, g1, b1, slotA);
    gemm_kernel<128,0><<<1152, 256, 0, stream>>>(slotA, wt_qkv, nullptr, nullptr, qkv, 2304, 768);
    vtrans_kernel<<<1536, 256, 0, stream>>>(qkv, vt);
    attn_kernel<<<768, 256, 0, stream>>>(qkv, vt, slotA);
    gemm_kernel<64,2><<<768, 256, 0, stream>>>(slotA, wt_o, nullptr, x, (void*)out, 768, 768);
    ln_kernel<<<M_, 256, 0, stream>>>(out, g2, b2, slotA);
    gemm_kernel<128,1><<<1536, 256, 0, stream>>>(slotA, wt_1, bW1, nullptr, ffm, 3072, 768);
    gemm_kernel<64,2><<<768, 256, 0, stream>>>(ffm, wt_2, bW2, out, (void*)out, 768, 3072);
}